// Round 3
// baseline (177.063 us; speedup 1.0000x reference)
//
#include <hip/hip_runtime.h>

#define HEIGHT 8
#define H_FM 128
#define W_FM 128
#define C_FM 32

typedef float f32x4 __attribute__((ext_vector_type(4)));

// One thread = one (box, v, u, channel-group-of-4).
// Layout: tid = ((b*HEIGHT + v)*MW + u)*(C/4) + cg  -> out f32x4 at tid*4.
// MW as template param: folds the %/ / into shifts for the MW=64 case.
template <int MW>
__global__ __launch_bounds__(256) void roi_rotate_kernel(
    const float* __restrict__ fm,      // (N, 128, 128, 32) f32
    const float* __restrict__ boxes,   // (B, 9) f32
    const int*   __restrict__ box_idx, // (B,) i32
    float*       __restrict__ out,     // crops (B,8,MW,32) then padded_width (B,)
    int B, float MWf)
{
    int tid = blockIdx.x * 256 + threadIdx.x;
    int cg  = tid & 7;          // channel group: c = cg*4
    int pix = tid >> 3;         // ((b*8 + v)*MW + u)
    int u   = pix % MW;
    int t2  = pix / MW;
    int v   = t2 & (HEIGHT - 1);
    int b   = t2 >> 3;
    if (b >= B) return;

    // Box parameters (wave-uniform; L1-cached)
    const float* bx = boxes + b * 9;
    float x1 = bx[0] * 0.25f, y1 = bx[1] * 0.25f;
    float x2 = bx[2] * 0.25f, y2 = bx[3] * 0.25f;
    float x4 = bx[6] * 0.25f, y4 = bx[7] * 0.25f;

    float box_w = x2 - x1;
    float box_h = y4 - y1;
    float width = (float)HEIGHT * box_w / fmaxf(box_h, 1e-6f);
    width = fminf(fmaxf(width, 1.0f), MWf);

    float uf = (float)u;
    f32x4 r = (f32x4)0.0f;

    // Padded region (uf >= width, ~2/3 of pixels): skip ALL gathers —
    // exec-masked lanes issue no memory ops. Only the zero store remains.
    if (uf < width) {
        float tu = uf / width;
        float tv = (float)v * (1.0f / (float)HEIGHT);
        float sx = x1 + tu * (x2 - x1) + tv * (x4 - x1);
        float sy = y1 + tu * (y2 - y1) + tv * (y4 - y1);

        float x0f = floorf(sx), y0f = floorf(sy);
        float wx = sx - x0f,    wy = sy - y0f;   // reference: from UNclipped floor
        int x0i = min(max((int)x0f, 0), W_FM - 1);
        int x1i = min(x0i + 1, W_FM - 1);
        int y0i = min(max((int)y0f, 0), H_FM - 1);
        int y1i = min(y0i + 1, H_FM - 1);

        int bi = box_idx[b];
        const float* base = fm + (size_t)bi * (H_FM * W_FM * C_FM);
        int c = cg * 4;

        const f32x4 g00 = *(const f32x4*)(base + (y0i * W_FM + x0i) * C_FM + c);
        const f32x4 g01 = *(const f32x4*)(base + (y0i * W_FM + x1i) * C_FM + c);
        const f32x4 g10 = *(const f32x4*)(base + (y1i * W_FM + x0i) * C_FM + c);
        const f32x4 g11 = *(const f32x4*)(base + (y1i * W_FM + x1i) * C_FM + c);

        float w00 = (1.0f - wy) * (1.0f - wx);
        float w01 = (1.0f - wy) * wx;
        float w10 = wy * (1.0f - wx);
        float w11 = wy * wx;

        r = w00 * g00 + w01 * g01 + w10 * g10 + w11 * g11;
    }

    // Write-once output: nontemporal so 134 MB of stores don't evict the
    // feature map from L2/LLC.
    __builtin_nontemporal_store(r, (f32x4*)(out + (size_t)pix * C_FM + cg * 4));

    // One lane per box writes padded_width.
    if (u == 0 && v == 0 && cg == 0) {
        out[(size_t)B * HEIGHT * MW * C_FM + b] = MWf - width;
    }
}

extern "C" void kernel_launch(void* const* d_in, const int* in_sizes, int n_in,
                              void* d_out, int out_size, void* d_ws, size_t ws_size,
                              hipStream_t stream) {
    const float* fm    = (const float*)d_in[0];
    const float* boxes = (const float*)d_in[1];
    const int*   bidx  = (const int*)d_in[2];

    int B  = in_sizes[2];                              // 2048
    int MW = (out_size - B) / (B * HEIGHT * C_FM);     // 64

    int total  = B * HEIGHT * MW * (C_FM / 4);         // threads
    int blocks = (total + 255) / 256;

    if (MW == 64) {
        roi_rotate_kernel<64><<<blocks, 256, 0, stream>>>(
            fm, boxes, bidx, (float*)d_out, B, (float)MW);
    } else if (MW == 32) {
        roi_rotate_kernel<32><<<blocks, 256, 0, stream>>>(
            fm, boxes, bidx, (float*)d_out, B, (float)MW);
    } else if (MW == 128) {
        roi_rotate_kernel<128><<<blocks, 256, 0, stream>>>(
            fm, boxes, bidx, (float*)d_out, B, (float)MW);
    } else {
        // generic fallback: reuse 64-layout math via runtime path not needed
        // for this problem (MW is 64), but keep a safe catch-all.
        roi_rotate_kernel<1><<<0, 0, 0, stream>>>(fm, boxes, bidx, (float*)d_out, B, (float)MW);
    }
}

// Round 4
// 173.933 us; speedup vs baseline: 1.0180x; 1.0180x over previous
//
#include <hip/hip_runtime.h>

#define HEIGHT 8
#define H_FM 128
#define W_FM 128
#define C_FM 32

typedef float f32x4 __attribute__((ext_vector_type(4)));

// One thread = one (box, v, u, channel-group-of-4).
// Layout: tid = ((b*HEIGHT + v)*MW + u)*(C/4) + cg  -> out f32x4 at tid*4.
// MW template: compile-time shifts for MW=64; MW==0 means runtime width.
template <int MW_CT>
__global__ __launch_bounds__(256) void roi_rotate_kernel(
    const float* __restrict__ fm,      // (N, 128, 128, 32) f32
    const float* __restrict__ boxes,   // (B, 9) f32
    const int*   __restrict__ box_idx, // (B,) i32
    float*       __restrict__ out,     // crops (B,8,MW,32) then padded_width (B,)
    int B, int MW_rt, float MWf)
{
    const int MW = MW_CT ? MW_CT : MW_rt;

    int tid = blockIdx.x * 256 + threadIdx.x;
    int cg  = tid & 7;          // channel group: c = cg*4
    int pix = tid >> 3;         // ((b*8 + v)*MW + u)
    int u   = pix % MW;
    int t2  = pix / MW;
    int v   = t2 & (HEIGHT - 1);
    int b   = t2 >> 3;
    if (b >= B) return;

    // Box parameters (wave-uniform for MW=64; scalar-cached)
    const float* bx = boxes + b * 9;
    float x1 = bx[0] * 0.25f, y1 = bx[1] * 0.25f;
    float x2 = bx[2] * 0.25f, y2 = bx[3] * 0.25f;
    float x4 = bx[6] * 0.25f, y4 = bx[7] * 0.25f;

    float box_w = x2 - x1;
    float box_h = y4 - y1;
    float width = (float)HEIGHT * box_w / fmaxf(box_h, 1e-6f);
    width = fminf(fmaxf(width, 1.0f), MWf);

    float uf = (float)u;
    f32x4 r = (f32x4)0.0f;

    // Padded region (uf >= width, ~2/3 of pixels): whole wave skips gathers.
    if (uf < width) {
        float tu = uf / width;
        float tv = (float)v * (1.0f / (float)HEIGHT);
        float sx = x1 + tu * (x2 - x1) + tv * (x4 - x1);
        float sy = y1 + tu * (y2 - y1) + tv * (y4 - y1);

        float x0f = floorf(sx), y0f = floorf(sy);
        float wx = sx - x0f,    wy = sy - y0f;   // from UNclipped floor (ref semantics)
        int x0i = min(max((int)x0f, 0), W_FM - 1);
        int x1i = min(x0i + 1, W_FM - 1);
        int y0i = min(max((int)y0f, 0), H_FM - 1);
        int y1i = min(y0i + 1, H_FM - 1);

        int bi = box_idx[b];
        const float* base = fm + (size_t)bi * (H_FM * W_FM * C_FM);
        int c = cg * 4;

        const f32x4 g00 = *(const f32x4*)(base + (y0i * W_FM + x0i) * C_FM + c);
        const f32x4 g01 = *(const f32x4*)(base + (y0i * W_FM + x1i) * C_FM + c);
        const f32x4 g10 = *(const f32x4*)(base + (y1i * W_FM + x0i) * C_FM + c);
        const f32x4 g11 = *(const f32x4*)(base + (y1i * W_FM + x1i) * C_FM + c);

        float w00 = (1.0f - wy) * (1.0f - wx);
        float w01 = (1.0f - wy) * wx;
        float w10 = wy * (1.0f - wx);
        float w11 = wy * wx;

        r = w00 * g00 + w01 * g01 + w10 * g10 + w11 * g11;
    }

    // R4 probe: PLAIN store (no nontemporal hint). The harness fill kernel
    // reaches 6.3 TB/s with plain stores; NT may have throttled ours.
    *(f32x4*)(out + (size_t)pix * C_FM + cg * 4) = r;

    // One lane per box writes padded_width.
    if (u == 0 && v == 0 && cg == 0) {
        out[(size_t)B * HEIGHT * MW * C_FM + b] = MWf - width;
    }
}

extern "C" void kernel_launch(void* const* d_in, const int* in_sizes, int n_in,
                              void* d_out, int out_size, void* d_ws, size_t ws_size,
                              hipStream_t stream) {
    const float* fm    = (const float*)d_in[0];
    const float* boxes = (const float*)d_in[1];
    const int*   bidx  = (const int*)d_in[2];

    int B  = in_sizes[2];                              // 2048
    int MW = (out_size - B) / (B * HEIGHT * C_FM);     // 64

    int total  = B * HEIGHT * MW * (C_FM / 4);         // threads
    int blocks = (total + 255) / 256;

    if (MW == 64) {
        roi_rotate_kernel<64><<<blocks, 256, 0, stream>>>(
            fm, boxes, bidx, (float*)d_out, B, MW, (float)MW);
    } else {
        roi_rotate_kernel<0><<<blocks, 256, 0, stream>>>(
            fm, boxes, bidx, (float*)d_out, B, MW, (float)MW);
    }
}

// Round 5
// 165.841 us; speedup vs baseline: 1.0677x; 1.0488x over previous
//
#include <hip/hip_runtime.h>

#define HEIGHT 8
#define H_FM 128
#define W_FM 128
#define C_FM 32

typedef float f32x4 __attribute__((ext_vector_type(4)));

// MW=64 specialization: one box = 8*64*8 = 4096 threads = exactly 16 blocks.
// b derives ONLY from blockIdx.x -> provably wave-uniform -> boxes/box_idx
// loads become s_load (scalar), not 7 redundant per-lane global_load_dword.
__global__ __launch_bounds__(256) void roi_rotate_64(
    const float* __restrict__ fm,      // (N, 128, 128, 32) f32
    const float* __restrict__ boxes,   // (B, 9) f32
    const int*   __restrict__ box_idx, // (B,) i32
    float*       __restrict__ out,     // crops (B,8,64,32) then padded_width (B,)
    int B, float MWf)
{
    const int b   = blockIdx.x >> 4;                       // scalar
    const int loc = ((blockIdx.x & 15) << 8) | threadIdx.x; // 0..4095
    const int cg  = loc & 7;            // channel group (c = cg*4)
    const int u   = (loc >> 3) & 63;
    const int v   = loc >> 9;

    // Scalar (SMEM) loads: b is uniform.
    const float* bx = boxes + b * 9;
    float x1 = bx[0] * 0.25f, y1 = bx[1] * 0.25f;
    float x2 = bx[2] * 0.25f, y2 = bx[3] * 0.25f;
    float x4 = bx[6] * 0.25f, y4 = bx[7] * 0.25f;
    int bi = box_idx[b];

    float box_w = x2 - x1;
    float box_h = y4 - y1;
    float width = (float)HEIGHT * box_w / fmaxf(box_h, 1e-6f);
    width = fminf(fmaxf(width, 1.0f), MWf);

    float uf = (float)u;
    f32x4 r = (f32x4)0.0f;

    if (uf < width) {
        float tu = uf / width;
        float tv = (float)v * (1.0f / (float)HEIGHT);
        float sx = x1 + tu * (x2 - x1) + tv * (x4 - x1);
        float sy = y1 + tu * (y2 - y1) + tv * (y4 - y1);

        float x0f = floorf(sx), y0f = floorf(sy);
        float wx = sx - x0f,    wy = sy - y0f;   // from UNclipped floor (ref semantics)
        int x0i = min(max((int)x0f, 0), W_FM - 1);
        int x1i = min(x0i + 1, W_FM - 1);
        int y0i = min(max((int)y0f, 0), H_FM - 1);
        int y1i = min(y0i + 1, H_FM - 1);

        const float* base = fm + (size_t)bi * (H_FM * W_FM * C_FM) + cg * 4;

        const f32x4 g00 = *(const f32x4*)(base + (y0i * W_FM + x0i) * C_FM);
        const f32x4 g01 = *(const f32x4*)(base + (y0i * W_FM + x1i) * C_FM);
        const f32x4 g10 = *(const f32x4*)(base + (y1i * W_FM + x0i) * C_FM);
        const f32x4 g11 = *(const f32x4*)(base + (y1i * W_FM + x1i) * C_FM);

        float w00 = (1.0f - wy) * (1.0f - wx);
        float w01 = (1.0f - wy) * wx;
        float w10 = wy * (1.0f - wx);
        float w11 = wy * wx;

        r = w00 * g00 + w01 * g01 + w10 * g10 + w11 * g11;
    }

    // out offset = ((b*8+v)*64+u)*32 + cg*4 = b*16384 + loc*4 (coalesced 16B/lane)
    *(f32x4*)(out + (size_t)b * 16384 + (size_t)loc * 4) = r;

    // One lane per box writes padded_width.
    if (loc == 0) {
        out[(size_t)B * HEIGHT * 64 * C_FM + b] = MWf - width;
    }
}

// Generic fallback (runtime MW) — same math, per-lane loads. Not the hot path.
__global__ __launch_bounds__(256) void roi_rotate_generic(
    const float* __restrict__ fm, const float* __restrict__ boxes,
    const int* __restrict__ box_idx, float* __restrict__ out,
    int B, int MW, float MWf)
{
    int tid = blockIdx.x * 256 + threadIdx.x;
    int cg  = tid & 7;
    int pix = tid >> 3;
    int u   = pix % MW;
    int t2  = pix / MW;
    int v   = t2 & (HEIGHT - 1);
    int b   = t2 >> 3;
    if (b >= B) return;

    const float* bx = boxes + b * 9;
    float x1 = bx[0] * 0.25f, y1 = bx[1] * 0.25f;
    float x2 = bx[2] * 0.25f, y2 = bx[3] * 0.25f;
    float x4 = bx[6] * 0.25f, y4 = bx[7] * 0.25f;

    float box_w = x2 - x1, box_h = y4 - y1;
    float width = (float)HEIGHT * box_w / fmaxf(box_h, 1e-6f);
    width = fminf(fmaxf(width, 1.0f), MWf);

    float uf = (float)u;
    f32x4 r = (f32x4)0.0f;
    if (uf < width) {
        float tu = uf / width;
        float tv = (float)v * (1.0f / (float)HEIGHT);
        float sx = x1 + tu * (x2 - x1) + tv * (x4 - x1);
        float sy = y1 + tu * (y2 - y1) + tv * (y4 - y1);
        float x0f = floorf(sx), y0f = floorf(sy);
        float wx = sx - x0f, wy = sy - y0f;
        int x0i = min(max((int)x0f, 0), W_FM - 1);
        int x1i = min(x0i + 1, W_FM - 1);
        int y0i = min(max((int)y0f, 0), H_FM - 1);
        int y1i = min(y0i + 1, H_FM - 1);
        const float* base = fm + (size_t)box_idx[b] * (H_FM * W_FM * C_FM) + cg * 4;
        const f32x4 g00 = *(const f32x4*)(base + (y0i * W_FM + x0i) * C_FM);
        const f32x4 g01 = *(const f32x4*)(base + (y0i * W_FM + x1i) * C_FM);
        const f32x4 g10 = *(const f32x4*)(base + (y1i * W_FM + x0i) * C_FM);
        const f32x4 g11 = *(const f32x4*)(base + (y1i * W_FM + x1i) * C_FM);
        float w00 = (1.0f - wy) * (1.0f - wx), w01 = (1.0f - wy) * wx;
        float w10 = wy * (1.0f - wx),          w11 = wy * wx;
        r = w00 * g00 + w01 * g01 + w10 * g10 + w11 * g11;
    }
    *(f32x4*)(out + (size_t)pix * C_FM + cg * 4) = r;
    if (u == 0 && v == 0 && cg == 0)
        out[(size_t)B * HEIGHT * MW * C_FM + b] = MWf - width;
}

extern "C" void kernel_launch(void* const* d_in, const int* in_sizes, int n_in,
                              void* d_out, int out_size, void* d_ws, size_t ws_size,
                              hipStream_t stream) {
    const float* fm    = (const float*)d_in[0];
    const float* boxes = (const float*)d_in[1];
    const int*   bidx  = (const int*)d_in[2];

    int B  = in_sizes[2];                              // 2048
    int MW = (out_size - B) / (B * HEIGHT * C_FM);     // 64

    if (MW == 64) {
        roi_rotate_64<<<B * 16, 256, 0, stream>>>(
            fm, boxes, bidx, (float*)d_out, B, 64.0f);
    } else {
        int total  = B * HEIGHT * MW * (C_FM / 4);
        int blocks = (total + 255) / 256;
        roi_rotate_generic<<<blocks, 256, 0, stream>>>(
            fm, boxes, bidx, (float*)d_out, B, MW, (float)MW);
    }
}

// Round 6
// 163.595 us; speedup vs baseline: 1.0823x; 1.0137x over previous
//
#include <hip/hip_runtime.h>

#define HEIGHT 8
#define H_FM 128
#define W_FM 128
#define C_FM 32

typedef float f32x4 __attribute__((ext_vector_type(4)));

// MW=64: thread = (b, u, cg); loops v=0..7. One box = 64*8 = 512 threads
// = 2 blocks of 256. b derives only from blockIdx.x -> scalar box loads.
// Validity (uf < width) depends only on u -> hoisted out of the v-loop:
// padded threads issue 8 zero stores and no gathers; valid threads amortize
// box math 8x and keep 8 gathers in flight (unroll 2 x 4 gathers).
__global__ __launch_bounds__(256) void roi_rotate_64(
    const float* __restrict__ fm,      // (N, 128, 128, 32) f32
    const float* __restrict__ boxes,   // (B, 9) f32
    const int*   __restrict__ box_idx, // (B,) i32
    float*       __restrict__ out,     // crops (B,8,64,32) then padded_width (B,)
    int B, float MWf)
{
    const int b    = blockIdx.x >> 1;          // scalar
    const int half = blockIdx.x & 1;           // u upper/lower 32
    const int tid  = threadIdx.x;
    const int cg   = tid & 7;                  // channel group (c = cg*4)
    const int u    = (half << 5) | (tid >> 3); // 0..63

    // Scalar (SMEM) loads.
    const float* bx = boxes + b * 9;
    float x1 = bx[0] * 0.25f, y1 = bx[1] * 0.25f;
    float x2 = bx[2] * 0.25f, y2 = bx[3] * 0.25f;
    float x4 = bx[6] * 0.25f, y4 = bx[7] * 0.25f;

    float width = (float)HEIGHT * (x2 - x1) / fmaxf(y4 - y1, 1e-6f);
    width = fminf(fmaxf(width, 1.0f), MWf);

    float uf = (float)u;
    // out base for this (b,u,cg); v stride = 64*32 = 2048 floats.
    float* outp = out + (size_t)b * 16384 + u * 32 + cg * 4;

    if (uf < width) {
        float tu  = uf / width;
        float ex  = x4 - x1, ey = y4 - y1;
        float sx0 = x1 + tu * (x2 - x1);   // reference association: (x1+tu*dx)+tv*ex
        float sy0 = y1 + tu * (y2 - y1);

        const float* base = fm + (size_t)box_idx[b] * (H_FM * W_FM * C_FM) + cg * 4;

        #pragma unroll 2
        for (int v = 0; v < HEIGHT; ++v) {
            float tv = (float)v * 0.125f;  // v/8 exact
            float sx = sx0 + tv * ex;
            float sy = sy0 + tv * ey;

            float x0f = floorf(sx), y0f = floorf(sy);
            float wx = sx - x0f,    wy = sy - y0f;   // from UNclipped floor
            int x0i = min(max((int)x0f, 0), W_FM - 1);
            int x1i = min(x0i + 1, W_FM - 1);
            int y0i = min(max((int)y0f, 0), H_FM - 1);
            int y1i = min(y0i + 1, H_FM - 1);

            const f32x4 g00 = *(const f32x4*)(base + (y0i * W_FM + x0i) * C_FM);
            const f32x4 g01 = *(const f32x4*)(base + (y0i * W_FM + x1i) * C_FM);
            const f32x4 g10 = *(const f32x4*)(base + (y1i * W_FM + x0i) * C_FM);
            const f32x4 g11 = *(const f32x4*)(base + (y1i * W_FM + x1i) * C_FM);

            float w00 = (1.0f - wy) * (1.0f - wx);
            float w01 = (1.0f - wy) * wx;
            float w10 = wy * (1.0f - wx);
            float w11 = wy * wx;

            *(f32x4*)(outp + v * 2048) = w00 * g00 + w01 * g01 + w10 * g10 + w11 * g11;
        }
    } else {
        #pragma unroll
        for (int v = 0; v < HEIGHT; ++v)
            *(f32x4*)(outp + v * 2048) = (f32x4)0.0f;
    }

    // One lane per box writes padded_width.
    if (tid == 0 && half == 0) {
        out[(size_t)B * (HEIGHT * 64 * C_FM) + b] = MWf - width;
    }
}

// Generic fallback (runtime MW) — per-pixel threads, same math.
__global__ __launch_bounds__(256) void roi_rotate_generic(
    const float* __restrict__ fm, const float* __restrict__ boxes,
    const int* __restrict__ box_idx, float* __restrict__ out,
    int B, int MW, float MWf)
{
    int tid = blockIdx.x * 256 + threadIdx.x;
    int cg  = tid & 7;
    int pix = tid >> 3;
    int u   = pix % MW;
    int t2  = pix / MW;
    int v   = t2 & (HEIGHT - 1);
    int b   = t2 >> 3;
    if (b >= B) return;

    const float* bx = boxes + b * 9;
    float x1 = bx[0] * 0.25f, y1 = bx[1] * 0.25f;
    float x2 = bx[2] * 0.25f, y2 = bx[3] * 0.25f;
    float x4 = bx[6] * 0.25f, y4 = bx[7] * 0.25f;

    float width = (float)HEIGHT * (x2 - x1) / fmaxf(y4 - y1, 1e-6f);
    width = fminf(fmaxf(width, 1.0f), MWf);

    float uf = (float)u;
    f32x4 r = (f32x4)0.0f;
    if (uf < width) {
        float tu = uf / width;
        float tv = (float)v * (1.0f / (float)HEIGHT);
        float sx = x1 + tu * (x2 - x1) + tv * (x4 - x1);
        float sy = y1 + tu * (y2 - y1) + tv * (y4 - y1);
        float x0f = floorf(sx), y0f = floorf(sy);
        float wx = sx - x0f, wy = sy - y0f;
        int x0i = min(max((int)x0f, 0), W_FM - 1);
        int x1i = min(x0i + 1, W_FM - 1);
        int y0i = min(max((int)y0f, 0), H_FM - 1);
        int y1i = min(y0i + 1, H_FM - 1);
        const float* base = fm + (size_t)box_idx[b] * (H_FM * W_FM * C_FM) + cg * 4;
        const f32x4 g00 = *(const f32x4*)(base + (y0i * W_FM + x0i) * C_FM);
        const f32x4 g01 = *(const f32x4*)(base + (y0i * W_FM + x1i) * C_FM);
        const f32x4 g10 = *(const f32x4*)(base + (y1i * W_FM + x0i) * C_FM);
        const f32x4 g11 = *(const f32x4*)(base + (y1i * W_FM + x1i) * C_FM);
        float w00 = (1.0f - wy) * (1.0f - wx), w01 = (1.0f - wy) * wx;
        float w10 = wy * (1.0f - wx),          w11 = wy * wx;
        r = w00 * g00 + w01 * g01 + w10 * g10 + w11 * g11;
    }
    *(f32x4*)(out + (size_t)pix * C_FM + cg * 4) = r;
    if (u == 0 && v == 0 && cg == 0)
        out[(size_t)B * HEIGHT * MW * C_FM + b] = MWf - width;
}

extern "C" void kernel_launch(void* const* d_in, const int* in_sizes, int n_in,
                              void* d_out, int out_size, void* d_ws, size_t ws_size,
                              hipStream_t stream) {
    const float* fm    = (const float*)d_in[0];
    const float* boxes = (const float*)d_in[1];
    const int*   bidx  = (const int*)d_in[2];

    int B  = in_sizes[2];                              // 2048
    int MW = (out_size - B) / (B * HEIGHT * C_FM);     // 64

    if (MW == 64) {
        roi_rotate_64<<<B * 2, 256, 0, stream>>>(
            fm, boxes, bidx, (float*)d_out, B, 64.0f);
    } else {
        int total  = B * HEIGHT * MW * (C_FM / 4);
        int blocks = (total + 255) / 256;
        roi_rotate_generic<<<blocks, 256, 0, stream>>>(
            fm, boxes, bidx, (float*)d_out, B, MW, (float)MW);
    }
}